// Round 18
// baseline (249.920 us; speedup 1.0000x reference)
//
#include <hip/hip_runtime.h>
#include <hip/hip_bf16.h>

#define NN    100000
#define EE    1600000
#define DF    64

typedef __bf16 bf16x8 __attribute__((ext_vector_type(8)));
typedef float  f32x4  __attribute__((ext_vector_type(4)));

// tanh-approx gelu, exp2-folded: x / (1 + 2^-(c1*x + c2*x^3))
__device__ __forceinline__ float gelu_f(float x) {
    float u2 = x * (2.302234849f + 0.102953097f * x * x);
    float s  = exp2f(-u2);
    return __fdividef(x, 1.0f + s);
}

__device__ __forceinline__ unsigned cvt_pk_bf16(float lo, float hi) {
    unsigned r;
    asm("v_cvt_pk_bf16_f32 %0, %1, %2" : "=v"(r) : "v"(lo), "v"(hi));
    return r;
}

// ---- kernel 0: seg via binary search, 2 edges per thread ----
// seg[e] = largest n with splits[n] <= e  (searchsorted-right - 1)
__global__ void it_seg(const int* __restrict__ splits, int* __restrict__ seg) {
    const int e0 = (blockIdx.x * 256 + threadIdx.x) * 2;   // grid*512 == EE exactly
    int n = 0;
    #pragma unroll
    for (int step = 65536; step >= 1; step >>= 1) {
        const int cand = n + step;
        if (cand <= NN - 1 && splits[cand] <= e0) n = cand;
    }
    int2 s;
    s.x = n;
    const int e1 = e0 + 1;
    while (n < NN - 1 && splits[n + 1] <= e1) n++;         // usually 0-1 steps
    s.y = n;
    *(int2*)(seg + e0) = s;
}

// ---- kernel 1: per-edge MLP (pure producer), h[e][c] bf16 ----
// fy row loads hoisted to group START: addresses depend only on q, and the
// ~600cy scattered-gather latency hides under MFMA0+gelu+transpose+MFMA1.
__global__ __launch_bounds__(256, 4)
void it_edge(const float* __restrict__ y, const float* __restrict__ fy,
             const float* __restrict__ W0, const float* __restrict__ b0,
             const float* __restrict__ W1, const float* __restrict__ b1,
             const int* __restrict__ nbr, const int* __restrict__ seg,
             __bf16* __restrict__ h)
{
    __shared__ __align__(16) int    nbL[4][64];
    __shared__ __align__(16) __bf16 aggW[4][64][8];
    __shared__ __align__(16) __bf16 hL[4][16][DF];

    const int t    = threadIdx.x;
    const int lane = t & 63;
    const int wv   = t >> 6;
    const int col  = lane & 15;
    const int kg   = lane >> 4;

    // ---- weight fragments (register-resident; validated layout) ----
    bf16x8 w0f[4];
    #pragma unroll
    for (int nt = 0; nt < 4; nt++)
        #pragma unroll
        for (int j = 0; j < 8; j++) {
            const int k = kg * 8 + j;
            float v = 0.0f;
            if (k < 6)       v = W0[k * DF + nt * 16 + col];
            else if (k == 6) v = b0[nt * 16 + col];
            w0f[nt][j] = (__bf16)v;
        }
    bf16x8 w1f[4][2];
    float  b1r[4];
    #pragma unroll
    for (int nt = 0; nt < 4; nt++) {
        b1r[nt] = b1[col * 4 + nt];
        #pragma unroll
        for (int kf = 0; kf < 2; kf++)
            #pragma unroll
            for (int j = 0; j < 8; j++)
                w1f[nt][kf][j] = (__bf16)W1[(kf * 32 + kg * 8 + j) * DF + col * 4 + nt];
    }

    // ---- stage this wave's 64 edges (E = grid*256 exactly, no tail) ----
    const int ebase = blockIdx.x * 256 + wv * 64;
    const int e     = ebase + lane;
    const int nb    = nbr[e];
    const int sge   = seg[e];
    nbL[wv][lane] = nb;
    bf16x8 ag = {};
    ag[0] = (__bf16)y[nb * 3 + 0];
    ag[1] = (__bf16)y[nb * 3 + 1];
    ag[2] = (__bf16)y[nb * 3 + 2];
    ag[3] = (__bf16)y[sge * 3 + 0];
    ag[4] = (__bf16)y[sge * 3 + 1];
    ag[5] = (__bf16)y[sge * 3 + 2];
    ag[6] = (__bf16)1.0f;               // bias slot (W0ext row 6 = b0)
    *(bf16x8*)&aggW[wv][lane][0] = ag;

    __bf16* const hw = &hL[wv][0][0];
    const int swz = (col & 7) << 4;

    #pragma unroll
    for (int g = 0; g < 4; g++) {
        const int gb = g * 16;
        const int4 q = *(const int4*)&nbL[wv][gb + kg * 4];

        // ---- fy gathers issued FIRST: latency hides under the MFMA chain ----
        const float4 fv0 = *(const float4*)(fy + (size_t)q.x * DF + col * 4);
        const float4 fv1 = *(const float4*)(fy + (size_t)q.y * DF + col * 4);
        const float4 fv2 = *(const float4*)(fy + (size_t)q.z * DF + col * 4);
        const float4 fv3 = *(const float4*)(fy + (size_t)q.w * DF + col * 4);

        bf16x8 a0 = {};
        if (kg == 0) a0 = *(const bf16x8*)&aggW[wv][gb + col][0];

        // layer 0 SWAPPED: lane holds h0^T[feat nt*16+kg*4+r][edge=col]
        f32x4 acc0[4] = {};
        #pragma unroll
        for (int nt = 0; nt < 4; nt++)
            acc0[nt] = __builtin_amdgcn_mfma_f32_16x16x32_bf16(w0f[nt], a0, acc0[nt], 0, 0, 0);

        // gelu + pack + 4x ds_write_b64 into hL[edge=col][feature] (swizzled)
        #pragma unroll
        for (int nt = 0; nt < 4; nt++) {
            const unsigned p0 = cvt_pk_bf16(gelu_f(acc0[nt][0]), gelu_f(acc0[nt][1]));
            const unsigned p1 = cvt_pk_bf16(gelu_f(acc0[nt][2]), gelu_f(acc0[nt][3]));
            const int off = col * 128 + ((nt * 32 + kg * 8) ^ swz);
            *(int2*)((char*)hw + off) = make_int2((int)p0, (int)p1);
        }
        bf16x8 af1[2];
        #pragma unroll
        for (int kf = 0; kf < 2; kf++) {
            const int off = col * 128 + ((kf * 64 + kg * 16) ^ swz);
            af1[kf] = *(const bf16x8*)((const char*)hw + off);
        }

        // layer 1: D1[edge=kg*4+r][c=col*4+nt], fp32 accum
        f32x4 acc[4] = {};
        #pragma unroll
        for (int nt = 0; nt < 4; nt++) {
            acc[nt] = __builtin_amdgcn_mfma_f32_16x16x32_bf16(af1[0], w1f[nt][0], acc[nt], 0, 0, 0);
            acc[nt] = __builtin_amdgcn_mfma_f32_16x16x32_bf16(af1[1], w1f[nt][1], acc[nt], 0, 0, 0);
        }

        // gate by prefetched fy rows, pack 4 bf16, coalesced 8B store per row
        const float4 fvr[4] = {fv0, fv1, fv2, fv3};
        #pragma unroll
        for (int r = 0; r < 4; r++) {
            const float4 fv = fvr[r];
            const unsigned u0 = cvt_pk_bf16((acc[0][r] + b1r[0]) * fv.x,
                                            (acc[1][r] + b1r[1]) * fv.y);
            const unsigned u1 = cvt_pk_bf16((acc[2][r] + b1r[2]) * fv.z,
                                            (acc[3][r] + b1r[3]) * fv.w);
            const size_t er = (size_t)(ebase + gb + kg * 4 + r);
            *(int2*)((char*)h + er * 128 + col * 8) = make_int2((int)u0, (int)u1);
        }
    }
}

// ---- kernel 2: per-node mean, one wave/node, 4 edge-rows per pass ----
__global__ void it_reduce(const int* __restrict__ splits,
                          const __bf16* __restrict__ h,
                          float* __restrict__ out)
{
    const int t    = threadIdx.x;
    const int lane = t & 63;
    const int wv   = t >> 6;
    const int n    = blockIdx.x * 4 + wv;          // grid*4 == NN exactly
    const int s0 = splits[n], s1 = splits[n + 1];
    const int par = lane >> 4;                     // 0..3: edge offset within pass
    const int cp  = lane & 15;                     // u64 col group: cols 4cp..4cp+3

    float a0 = 0.f, a1 = 0.f, a2 = 0.f, a3 = 0.f;
    for (int e = s0 + par; e < s1; e += 4) {
        const unsigned long long u =
            *(const unsigned long long*)((const char*)h + (size_t)e * 128 + cp * 8);
        const unsigned lo = (unsigned)u, hi = (unsigned)(u >> 32);
        a0 += __uint_as_float(lo << 16);
        a1 += __uint_as_float(lo & 0xffff0000u);
        a2 += __uint_as_float(hi << 16);
        a3 += __uint_as_float(hi & 0xffff0000u);
    }
    a0 += __shfl_xor(a0, 16); a0 += __shfl_xor(a0, 32);
    a1 += __shfl_xor(a1, 16); a1 += __shfl_xor(a1, 32);
    a2 += __shfl_xor(a2, 16); a2 += __shfl_xor(a2, 32);
    a3 += __shfl_xor(a3, 16); a3 += __shfl_xor(a3, 32);

    if (lane < 16) {
        const int cnt = s1 - s0;
        const float inv = (cnt > 0) ? __fdividef(1.0f, (float)cnt) : 0.0f;
        float4 v; v.x = a0 * inv; v.y = a1 * inv; v.z = a2 * inv; v.w = a3 * inv;
        *(float4*)(out + (size_t)n * DF + cp * 4) = v;
    }
}

// ============================ launcher ============================

extern "C" void kernel_launch(void* const* d_in, const int* in_sizes, int n_in,
                              void* d_out, int out_size, void* d_ws, size_t ws_size,
                              hipStream_t stream) {
    const float* y   = (const float*)d_in[0];
    const float* fyv = (const float*)d_in[1];
    const float* W0  = (const float*)d_in[2];
    const float* b0  = (const float*)d_in[3];
    const float* W1  = (const float*)d_in[4];
    const float* b1  = (const float*)d_in[5];
    const int*   nb  = (const int*)d_in[6];   // harness delivers integer inputs as int32
    const int*   sp  = (const int*)d_in[7];

    const size_t SEG_BYTES = (size_t)EE * 4;              // 6.4 MB
    int*    seg = (int*)d_ws;
    __bf16* h   = (__bf16*)((char*)d_ws + SEG_BYTES);     // 204.8 MB (ws verified >= 211 MB)

    it_seg   <<<EE / 512, 256, 0, stream>>>(sp, seg);
    it_edge  <<<EE / 256, 256, 0, stream>>>(y, fyv, W0, b0, W1, b1, nb, seg, h);
    it_reduce<<<NN / 4,   256, 0, stream>>>(sp, h, (float*)d_out);
}

// Round 19
// 176.871 us; speedup vs baseline: 1.4130x; 1.4130x over previous
//
#include <hip/hip_runtime.h>
#include <hip/hip_bf16.h>

#define NN    100000
#define EE    1600000
#define DF    64
#define BPB   5          // edge-batches (of 256) per block; EE / (256*BPB) = 1250 exact

typedef __bf16 bf16x8 __attribute__((ext_vector_type(8)));
typedef float  f32x4  __attribute__((ext_vector_type(4)));

// tanh-approx gelu, exp2-folded: x / (1 + 2^-(c1*x + c2*x^3))
__device__ __forceinline__ float gelu_f(float x) {
    float u2 = x * (2.302234849f + 0.102953097f * x * x);
    float s  = exp2f(-u2);
    return __fdividef(x, 1.0f + s);
}

__device__ __forceinline__ unsigned cvt_pk_bf16(float lo, float hi) {
    unsigned r;
    asm("v_cvt_pk_bf16_f32 %0, %1, %2" : "=v"(r) : "v"(lo), "v"(hi));
    return r;
}

// ---- kernel 0: seg via binary search, 2 edges per thread ----
__global__ void it_seg(const int* __restrict__ splits, int* __restrict__ seg) {
    const int e0 = (blockIdx.x * 256 + threadIdx.x) * 2;   // grid*512 == EE exactly
    int n = 0;
    #pragma unroll
    for (int step = 65536; step >= 1; step >>= 1) {
        const int cand = n + step;
        if (cand <= NN - 1 && splits[cand] <= e0) n = cand;
    }
    int2 s;
    s.x = n;
    const int e1 = e0 + 1;
    while (n < NN - 1 && splits[n + 1] <= e1) n++;         // usually 0-1 steps
    s.y = n;
    *(int2*)(seg + e0) = s;
}

// ---- kernel 1: per-edge MLP (pure producer), h[e][c] bf16 ----
// Each block runs BPB sequential 256-edge batches so the ~100-word weight
// prologue is amortized 5x. `#pragma unroll 1` keeps the batch loop from
// being software-pipelined into extra live registers (the working set at
// (256,4) is exactly full — R8/R10/R15/R18 all spilled on +state).
__global__ __launch_bounds__(256, 4)
void it_edge(const float* __restrict__ y, const float* __restrict__ fy,
             const float* __restrict__ W0, const float* __restrict__ b0,
             const float* __restrict__ W1, const float* __restrict__ b1,
             const int* __restrict__ nbr, const int* __restrict__ seg,
             __bf16* __restrict__ h)
{
    __shared__ __align__(16) int    nbL[4][64];
    __shared__ __align__(16) __bf16 aggW[4][64][8];
    __shared__ __align__(16) __bf16 hL[4][16][DF];

    const int t    = threadIdx.x;
    const int lane = t & 63;
    const int wv   = t >> 6;
    const int col  = lane & 15;
    const int kg   = lane >> 4;

    // ---- weight fragments (register-resident; validated layout) ----
    bf16x8 w0f[4];
    #pragma unroll
    for (int nt = 0; nt < 4; nt++)
        #pragma unroll
        for (int j = 0; j < 8; j++) {
            const int k = kg * 8 + j;
            float v = 0.0f;
            if (k < 6)       v = W0[k * DF + nt * 16 + col];
            else if (k == 6) v = b0[nt * 16 + col];
            w0f[nt][j] = (__bf16)v;
        }
    bf16x8 w1f[4][2];
    float  b1r[4];
    #pragma unroll
    for (int nt = 0; nt < 4; nt++) {
        b1r[nt] = b1[col * 4 + nt];
        #pragma unroll
        for (int kf = 0; kf < 2; kf++)
            #pragma unroll
            for (int j = 0; j < 8; j++)
                w1f[nt][kf][j] = (__bf16)W1[(kf * 32 + kg * 8 + j) * DF + col * 4 + nt];
    }

    __bf16* const hw = &hL[wv][0][0];
    const int swz = (col & 7) << 4;

    #pragma unroll 1
    for (int bb = 0; bb < BPB; bb++) {
        // ---- stage this wave's 64 edges (E = grid*256*BPB exactly, no tail) ----
        const int ebase = (blockIdx.x * BPB + bb) * 256 + wv * 64;
        const int e     = ebase + lane;
        const int nb    = nbr[e];
        const int sge   = seg[e];
        nbL[wv][lane] = nb;
        bf16x8 ag = {};
        ag[0] = (__bf16)y[nb * 3 + 0];
        ag[1] = (__bf16)y[nb * 3 + 1];
        ag[2] = (__bf16)y[nb * 3 + 2];
        ag[3] = (__bf16)y[sge * 3 + 0];
        ag[4] = (__bf16)y[sge * 3 + 1];
        ag[5] = (__bf16)y[sge * 3 + 2];
        ag[6] = (__bf16)1.0f;               // bias slot (W0ext row 6 = b0)
        *(bf16x8*)&aggW[wv][lane][0] = ag;  // wave-private: same-wave DS ordering

        #pragma unroll
        for (int g = 0; g < 4; g++) {
            const int gb = g * 16;
            const int4 q = *(const int4*)&nbL[wv][gb + kg * 4];

            bf16x8 a0 = {};
            if (kg == 0) a0 = *(const bf16x8*)&aggW[wv][gb + col][0];

            // layer 0 SWAPPED: lane holds h0^T[feat nt*16+kg*4+r][edge=col]
            f32x4 acc0[4] = {};
            #pragma unroll
            for (int nt = 0; nt < 4; nt++)
                acc0[nt] = __builtin_amdgcn_mfma_f32_16x16x32_bf16(w0f[nt], a0, acc0[nt], 0, 0, 0);

            // gelu + pack + 4x ds_write_b64 into hL[edge=col][feature] (swizzled)
            #pragma unroll
            for (int nt = 0; nt < 4; nt++) {
                const unsigned p0 = cvt_pk_bf16(gelu_f(acc0[nt][0]), gelu_f(acc0[nt][1]));
                const unsigned p1 = cvt_pk_bf16(gelu_f(acc0[nt][2]), gelu_f(acc0[nt][3]));
                const int off = col * 128 + ((nt * 32 + kg * 8) ^ swz);
                *(int2*)((char*)hw + off) = make_int2((int)p0, (int)p1);
            }
            bf16x8 af1[2];
            #pragma unroll
            for (int kf = 0; kf < 2; kf++) {
                const int off = col * 128 + ((kf * 64 + kg * 16) ^ swz);
                af1[kf] = *(const bf16x8*)((const char*)hw + off);
            }

            // layer 1: D1[edge=kg*4+r][c=col*4+nt], fp32 accum
            f32x4 acc[4] = {};
            #pragma unroll
            for (int nt = 0; nt < 4; nt++) {
                acc[nt] = __builtin_amdgcn_mfma_f32_16x16x32_bf16(af1[0], w1f[nt][0], acc[nt], 0, 0, 0);
                acc[nt] = __builtin_amdgcn_mfma_f32_16x16x32_bf16(af1[1], w1f[nt][1], acc[nt], 0, 0, 0);
            }

            // gate by fy row, pack 4 bf16, coalesced 8B store per edge-row
            #pragma unroll
            for (int r = 0; r < 4; r++) {
                const int qq = (&q.x)[r];
                const float4 fv = *(const float4*)(fy + (size_t)qq * DF + col * 4);
                const unsigned u0 = cvt_pk_bf16((acc[0][r] + b1r[0]) * fv.x,
                                                (acc[1][r] + b1r[1]) * fv.y);
                const unsigned u1 = cvt_pk_bf16((acc[2][r] + b1r[2]) * fv.z,
                                                (acc[3][r] + b1r[3]) * fv.w);
                const size_t er = (size_t)(ebase + gb + kg * 4 + r);
                *(int2*)((char*)h + er * 128 + col * 8) = make_int2((int)u0, (int)u1);
            }
        }
    }
}

// ---- kernel 2: per-node mean, one wave/node, 4 edge-rows per pass ----
__global__ void it_reduce(const int* __restrict__ splits,
                          const __bf16* __restrict__ h,
                          float* __restrict__ out)
{
    const int t    = threadIdx.x;
    const int lane = t & 63;
    const int wv   = t >> 6;
    const int n    = blockIdx.x * 4 + wv;          // grid*4 == NN exactly
    const int s0 = splits[n], s1 = splits[n + 1];
    const int par = lane >> 4;                     // 0..3: edge offset within pass
    const int cp  = lane & 15;                     // u64 col group: cols 4cp..4cp+3

    float a0 = 0.f, a1 = 0.f, a2 = 0.f, a3 = 0.f;
    for (int e = s0 + par; e < s1; e += 4) {
        const unsigned long long u =
            *(const unsigned long long*)((const char*)h + (size_t)e * 128 + cp * 8);
        const unsigned lo = (unsigned)u, hi = (unsigned)(u >> 32);
        a0 += __uint_as_float(lo << 16);
        a1 += __uint_as_float(lo & 0xffff0000u);
        a2 += __uint_as_float(hi << 16);
        a3 += __uint_as_float(hi & 0xffff0000u);
    }
    a0 += __shfl_xor(a0, 16); a0 += __shfl_xor(a0, 32);
    a1 += __shfl_xor(a1, 16); a1 += __shfl_xor(a1, 32);
    a2 += __shfl_xor(a2, 16); a2 += __shfl_xor(a2, 32);
    a3 += __shfl_xor(a3, 16); a3 += __shfl_xor(a3, 32);

    if (lane < 16) {
        const int cnt = s1 - s0;
        const float inv = (cnt > 0) ? __fdividef(1.0f, (float)cnt) : 0.0f;
        float4 v; v.x = a0 * inv; v.y = a1 * inv; v.z = a2 * inv; v.w = a3 * inv;
        *(float4*)(out + (size_t)n * DF + cp * 4) = v;
    }
}

// ============================ launcher ============================

extern "C" void kernel_launch(void* const* d_in, const int* in_sizes, int n_in,
                              void* d_out, int out_size, void* d_ws, size_t ws_size,
                              hipStream_t stream) {
    const float* y   = (const float*)d_in[0];
    const float* fyv = (const float*)d_in[1];
    const float* W0  = (const float*)d_in[2];
    const float* b0  = (const float*)d_in[3];
    const float* W1  = (const float*)d_in[4];
    const float* b1  = (const float*)d_in[5];
    const int*   nb  = (const int*)d_in[6];   // harness delivers integer inputs as int32
    const int*   sp  = (const int*)d_in[7];

    const size_t SEG_BYTES = (size_t)EE * 4;              // 6.4 MB
    int*    seg = (int*)d_ws;
    __bf16* h   = (__bf16*)((char*)d_ws + SEG_BYTES);     // 204.8 MB (ws verified >= 211 MB)

    it_seg   <<<EE / 512,         256, 0, stream>>>(sp, seg);
    it_edge  <<<EE / (256 * BPB), 256, 0, stream>>>(y, fyv, W0, b0, W1, b1, nb, seg, h);
    it_reduce<<<NN / 4,           256, 0, stream>>>(sp, h, (float*)d_out);
}